// Round 6
// baseline (342.611 us; speedup 1.0000x reference)
//
#include <hip/hip_runtime.h>
#include <hip/hip_cooperative_groups.h>
#include <hip/hip_bf16.h>
#include <stdint.h>

namespace cg = cooperative_groups;

#define NN 8192
#define DD 128

#define NBUCK 256          // bucket = s >> 5 (32 rows per bucket); also grid size
#define CHUNK 4096         // edges per partition chunk
#define SEGC 48            // per-(chunk,bucket) segment capacity (mean 16)
#define PCAP 128           // per-bucket passer capacity (mean ~8)

typedef __bf16 bf16x8 __attribute__((ext_vector_type(8)));
typedef float  f32x4  __attribute__((ext_vector_type(4)));

__device__ inline bf16x8 ld_bf16x8(const float* __restrict__ p) {
    float4 u0 = *(const float4*)p;
    float4 u1 = *(const float4*)(p + 4);
    bf16x8 r;
    r[0] = (__bf16)u0.x; r[1] = (__bf16)u0.y; r[2] = (__bf16)u0.z; r[3] = (__bf16)u0.w;
    r[4] = (__bf16)u1.x; r[5] = (__bf16)u1.y; r[6] = (__bf16)u1.z; r[7] = (__bf16)u1.w;
    return r;
}

// split fp32x8 into bf16 hi + lo residual (3-term MFMA ~ fp32 accuracy)
__device__ inline void ld_split(const float* __restrict__ p, bf16x8& h, bf16x8& l) {
    float4 u0 = *(const float4*)p;
    float4 u1 = *(const float4*)(p + 4);
    float v[8] = {u0.x, u0.y, u0.z, u0.w, u1.x, u1.y, u1.z, u1.w};
#pragma unroll
    for (int i = 0; i < 8; ++i) {
        __bf16 hh = (__bf16)v[i];
        h[i] = hh;
        l[i] = (__bf16)(v[i] - (float)hh);
    }
}

// phase-overlaid LDS
struct P1 {
    int cnt[NBUCK];
    int sc[2][NBUCK];
    int startS[NBUCK];
    int cur[NBUCK];
    uint32_t stage[CHUNK];
};                                      // ~21.5 KB
struct P2 {
    uint32_t bmap[8192];                // 32 KB
    uint32_t seen[8192];                // 32 KB
    uint32_t pass[PCAP];
    float xs[8][DD];
    float xd[8][DD];
    float red[8][2];
    int pc;
};                                      // ~72.6 KB
union ShU { P1 p1; P2 p2; };

// single fused kernel; phases [pbeg..pend]. Cooperative launch runs (0,2)
// with grid.sync between phases; fallback launches (0,0),(1,1),(2,2) plain.
__global__ __launch_bounds__(1024) void fused_all(
    const float* __restrict__ x,
    const int* __restrict__ ei1, int e1,
    const int* __restrict__ ei2, int e2,
    const int* __restrict__ mask, int em,
    const float* __restrict__ Wq, const float* __restrict__ Wk,
    const float* __restrict__ Wv,
    const float* __restrict__ Wg0, const float* __restrict__ Wg1,
    float* __restrict__ M, float* __restrict__ z, float* __restrict__ y,
    int* __restrict__ c2g,
    uint32_t* __restrict__ segM, uint32_t* __restrict__ seg1,
    uint32_t* __restrict__ seg2, int* __restrict__ counts,
    int nbm, int nb1, int nb2, float inv_np1, float coef_x,
    float* __restrict__ out, int pbeg, int pend) {
    __shared__ ShU sh;
    int b = blockIdx.x;
    int t = threadIdx.x;
    int npart = nbm + nb1 + nb2;
    cg::grid_group grid = cg::this_grid();

    for (int ph = pbeg; ph <= pend; ++ph) {
        if (ph == 0) {
            // ---------------- phase 1: partition + M-gemm + zero ------------
            P1& p = sh.p1;
            for (int pb = b; pb < npart; pb += gridDim.x) {
                const int* src; int ne, ch; uint32_t* seg; int* cnts;
                if (pb < nbm)            { src = mask; ne = em; ch = pb;             seg = segM; cnts = counts; }
                else if (pb < nbm + nb1) { src = ei1;  ne = e1; ch = pb - nbm;       seg = seg1; cnts = counts + nbm * NBUCK; }
                else                     { src = ei2;  ne = e2; ch = pb - nbm - nb1; seg = seg2; cnts = counts + (nbm + nb1) * NBUCK; }
                int base = ch * CHUNK;
                int n = ne - base;
                if (n > CHUNK) n = CHUNK;

                if (t < NBUCK) p.cnt[t] = 0;
                __syncthreads();

                uint32_t pk[4];
#pragma unroll
                for (int k = 0; k < 4; ++k) {
                    int i = t + k * 1024;
                    if (i < n) {
                        int s = src[base + i];
                        int d = src[ne + base + i];
                        pk[k] = ((uint32_t)s << 13) | (uint32_t)d;
                        atomicAdd(&p.cnt[pk[k] >> 18], 1);
                    } else pk[k] = 0xFFFFFFFFu;
                }
                __syncthreads();

                // inclusive scan over 256 bucket counts (threads 0..255)
                if (t < NBUCK) p.sc[0][t] = p.cnt[t];
                __syncthreads();
                int sb = 0;
                for (int off = 1; off < NBUCK; off <<= 1) {
                    int d2 = sb ^ 1;
                    if (t < NBUCK)
                        p.sc[d2][t] = (t >= off) ? p.sc[sb][t] + p.sc[sb][t - off]
                                                 : p.sc[sb][t];
                    sb = d2;
                    __syncthreads();
                }
                if (t < NBUCK) {
                    int sv = t ? p.sc[sb][t - 1] : 0;
                    p.startS[t] = sv;
                    p.cur[t] = sv;
                    cnts[ch * NBUCK + t] = min(p.cnt[t], SEGC);
                }
                __syncthreads();

                // bucket-sort into LDS
#pragma unroll
                for (int k = 0; k < 4; ++k) {
                    if (pk[k] != 0xFFFFFFFFu) {
                        int bb = pk[k] >> 18;
                        int pos = atomicAdd(&p.cur[bb], 1);
                        p.stage[pos] = pk[k];
                    }
                }
                __syncthreads();

                // coalesced flush to deterministic segments
                for (int i = t; i < n; i += 1024) {
                    uint32_t v = p.stage[i];
                    int bb = v >> 18;
                    int off = i - p.startS[bb];
                    if (off < SEGC) seg[(ch * NBUCK + bb) * SEGC + off] = v;
                }
                __syncthreads();
            }
            // extras: threads 0..63 -> 64 M elements; rest -> zero z|y (+c2)
            if (t < 64) {
                int m = b * 64 + t;
                int c = m >> 7, e = m & 127;
                float acc = 0.f;
#pragma unroll 8
                for (int a = 0; a < DD; ++a)
                    acc += Wq[a * DD + c] * Wk[a * DD + e];
                M[c * DD + e] = acc;
            } else {
                if (b == 0 && t == 64) *c2g = 0;
                float4* zy = (float4*)z;   // z and y are contiguous (8 MB)
                for (int i = b * 960 + (t - 64); i < 524288; i += 245760)
                    zy[i] = make_float4(0.f, 0.f, 0.f, 0.f);
            }
        } else if (ph == 1) {
            // ---------------- phase 2: per-bucket filter + fused scatter ----
            P2& p = sh.p2;
            const int* cntM  = counts;
            const int* cnt1c = counts + nbm * NBUCK;
            const int* cnt2c = counts + (nbm + nb1) * NBUCK;

            for (int i = t; i < 8192; i += 1024) { p.bmap[i] = 0; p.seen[i] = 0; }
            if (t == 0) p.pc = 0;
            __syncthreads();

            int slotsM = nbm * SEGC;
            for (int i = t; i < slotsM; i += 1024) {
                int ch = i / SEGC, j = i - ch * SEGC;
                if (j < cntM[ch * NBUCK + b]) {
                    uint32_t pk = segM[(ch * NBUCK + b) * SEGC + j];
                    uint32_t bi = pk & 0x3FFFFu;
                    atomicOr(&p.bmap[bi >> 5], 1u << (bi & 31));
                }
            }
            __syncthreads();

            int slots1 = nb1 * SEGC;
            for (int i = t; i < slots1; i += 1024) {
                int ch = i / SEGC, j = i - ch * SEGC;
                if (j < cnt1c[ch * NBUCK + b]) {
                    uint32_t pk = seg1[(ch * NBUCK + b) * SEGC + j];
                    uint32_t bi = pk & 0x3FFFFu;
                    uint32_t m = 1u << (bi & 31);
                    if (p.bmap[bi >> 5] & m) {
                        uint32_t old = atomicOr(&p.seen[bi >> 5], m);
                        if (!(old & m)) {
                            int pp = atomicAdd(&p.pc, 1);
                            if (pp < PCAP) p.pass[pp] = pk;
                        }
                    }
                }
            }
            __syncthreads();
            int np = min(p.pc, PCAP);
            int g = t >> 7, c = t & 127;

            // A1: z[d] += x[s], 8 edges in parallel
            for (int p0 = 0; p0 < np; p0 += 8) {
                int e = p0 + g;
                if (e < np) {
                    uint32_t pk = p.pass[e];
                    int s = pk >> 13, d = pk & 8191;
                    atomicAdd(&z[d * DD + c], x[s * DD + c]);
                }
            }
            __syncthreads();
            if (t == 0) p.pc = 0;
            for (int i = t; i < 8192; i += 1024) p.seen[i] = 0;
            __syncthreads();

            int slots2 = nb2 * SEGC;
            for (int i = t; i < slots2; i += 1024) {
                int ch = i / SEGC, j = i - ch * SEGC;
                if (j < cnt2c[ch * NBUCK + b]) {
                    uint32_t pk = seg2[(ch * NBUCK + b) * SEGC + j];
                    uint32_t bi = pk & 0x3FFFFu;
                    uint32_t m = 1u << (bi & 31);
                    if (p.bmap[bi >> 5] & m) {
                        uint32_t old = atomicOr(&p.seen[bi >> 5], m);
                        if (!(old & m)) {
                            int pp = atomicAdd(&p.pc, 1);
                            if (pp < PCAP) p.pass[pp] = pk;
                        }
                    }
                }
            }
            __syncthreads();
            np = min(p.pc, PCAP);
            if (t == 0) atomicAdd(c2g, np);

            // A2: y[d] += (x[d] @ M @ x[s]) * x[s]
            for (int p0 = 0; p0 < np; p0 += 8) {
                __syncthreads();
                int e = p0 + g;
                bool val = e < np;
                uint32_t pk = val ? p.pass[e] : 0;
                int s = pk >> 13, d = pk & 8191;
                if (val) {
                    p.xs[g][c] = x[s * DD + c];
                    p.xd[g][c] = x[d * DD + c];
                }
                __syncthreads();
                if (val) {
                    float acc = 0.f;
#pragma unroll 8
                    for (int a = 0; a < DD; ++a)
                        acc += p.xd[g][a] * M[a * DD + c];
                    float part = acc * p.xs[g][c];
                    for (int off2 = 32; off2; off2 >>= 1)
                        part += __shfl_down(part, off2, 64);
                    if ((c & 63) == 0) p.red[g][c >> 6] = part;
                }
                __syncthreads();
                if (val) {
                    float se = p.red[g][0] + p.red[g][1];
                    atomicAdd(&y[d * DD + c], se * p.xs[g][c]);
                }
            }
        } else {
            // ---------------- phase 3: epilogue (16-col strips per wave) ----
            int wid = b * 16 + (t >> 6);       // 4096 waves = 512 tiles x 8 strips
            int lane = t & 63;
            int tile = wid >> 3;
            int strip = wid & 7;
            int i16 = lane & 15, kg = lane >> 4;
            int rowbase = tile * 16, colbase = strip * 16;

            f32x4 acc = {}, acc2 = {};
#pragma unroll
            for (int kk = 0; kk < 8; ++kk) {
                const float* src = (kk < 4) ? x : z;
                const float* W   = (kk < 4) ? Wg0 : Wg1;
                int kofs = (kk & 3) * 32 + kg * 8;
                bf16x8 a  = ld_bf16x8(src + (rowbase + i16) * DD + kofs);
                bf16x8 b0 = ld_bf16x8(W + (colbase + i16) * DD + kofs);
                acc = __builtin_amdgcn_mfma_f32_16x16x32_bf16(a, b0, acc, 0, 0, 0);
            }
#pragma unroll
            for (int kk = 0; kk < 4; ++kk) {
                int kofs = kk * 32 + kg * 8;
                bf16x8 yh, yl, wh, wl;
                ld_split(y + (rowbase + i16) * DD + kofs, yh, yl);
                ld_split(Wv + (colbase + i16) * DD + kofs, wh, wl);
                acc2 = __builtin_amdgcn_mfma_f32_16x16x32_bf16(yh, wh, acc2, 0, 0, 0);
                acc2 = __builtin_amdgcn_mfma_f32_16x16x32_bf16(yh, wl, acc2, 0, 0, 0);
                acc2 = __builtin_amdgcn_mfma_f32_16x16x32_bf16(yl, wh, acc2, 0, 0, 0);
            }
            float scale2 = (float)NN / (float)(*c2g);
#pragma unroll
            for (int r = 0; r < 4; ++r) {
                int row = rowbase + kg * 4 + r;
                int col = colbase + i16;
                float xv = x[row * DD + col];
                out[row * DD + col] = acc[r] * inv_np1 + coef_x * xv
                                    - acc2[r] * scale2;
            }
        }
        if (ph < pend) {
            __threadfence();
            grid.sync();
        }
    }
}

// ---- host ------------------------------------------------------------------

extern "C" void kernel_launch(void* const* d_in, const int* in_sizes, int n_in,
                              void* d_out, int out_size, void* d_ws, size_t ws_size,
                              hipStream_t stream) {
    const float* x   = (const float*)d_in[0];
    const int* ei1   = (const int*)d_in[1];
    const int* ei2   = (const int*)d_in[2];
    const int* mask  = (const int*)d_in[3];
    const float* Wg0 = (const float*)d_in[4];
    const float* Wg1 = (const float*)d_in[5];
    const float* Wq  = (const float*)d_in[6];
    const float* Wk  = (const float*)d_in[7];
    const float* Wv  = (const float*)d_in[8];
    float* out = (float*)d_out;

    int e1 = in_sizes[1] / 2;
    int e2 = in_sizes[2] / 2;
    int em = in_sizes[3] / 2;
    float np1 = (float)em / (float)NN;
    float inv1 = 1.0f / np1;
    float coefx = (np1 - 1.0f) * inv1;

    int nbm = (em + CHUNK - 1) / CHUNK;   // 128
    int nb1 = (e1 + CHUNK - 1) / CHUNK;   // 64
    int nb2 = (e2 + CHUNK - 1) / CHUNK;   // 64
    int npart = nbm + nb1 + nb2;          // 256 == grid

    char* ws = (char*)d_ws;
    const size_t O_Z    = 0;                                   // 4 MB (zeroed ph1)
    const size_t O_Y    = 4194304;                             // 4 MB (zeroed ph1)
    const size_t O_M    = 8388608;                             // 64 KB
    const size_t O_C2   = O_M + 65536;                         // 64 B
    const size_t O_CNTS = O_C2 + 64;                           // npart*256*4
    const size_t O_SEGM = O_CNTS + (size_t)npart * NBUCK * 4;
    const size_t O_SEG1 = O_SEGM + (size_t)nbm * NBUCK * SEGC * 4;
    const size_t O_SEG2 = O_SEG1 + (size_t)nb1 * NBUCK * SEGC * 4;
    // end ~ 21.3 MB

    float*    z     = (float*)(ws + O_Z);
    float*    y     = (float*)(ws + O_Y);
    float*    M     = (float*)(ws + O_M);
    int*      c2    = (int*)(ws + O_C2);
    int*      cnts  = (int*)(ws + O_CNTS);
    uint32_t* segM  = (uint32_t*)(ws + O_SEGM);
    uint32_t* seg1  = (uint32_t*)(ws + O_SEG1);
    uint32_t* seg2  = (uint32_t*)(ws + O_SEG2);

    int pbeg = 0, pend = 2;
    void* args[] = {
        (void*)&x, (void*)&ei1, (void*)&e1, (void*)&ei2, (void*)&e2,
        (void*)&mask, (void*)&em, (void*)&Wq, (void*)&Wk, (void*)&Wv,
        (void*)&Wg0, (void*)&Wg1, (void*)&M, (void*)&z, (void*)&y,
        (void*)&c2, (void*)&segM, (void*)&seg1, (void*)&seg2, (void*)&cnts,
        (void*)&nbm, (void*)&nb1, (void*)&nb2, (void*)&inv1, (void*)&coefx,
        (void*)&out, (void*)&pbeg, (void*)&pend
    };
    hipError_t err = hipLaunchCooperativeKernel(
        (const void*)fused_all, dim3(NBUCK), dim3(1024), args, 0, stream);
    if (err != hipSuccess) {
        // fallback: same kernel, one phase per plain dispatch
        fused_all<<<NBUCK, 1024, 0, stream>>>(
            x, ei1, e1, ei2, e2, mask, em, Wq, Wk, Wv, Wg0, Wg1,
            M, z, y, c2, segM, seg1, seg2, cnts, nbm, nb1, nb2,
            inv1, coefx, out, 0, 0);
        fused_all<<<NBUCK, 1024, 0, stream>>>(
            x, ei1, e1, ei2, e2, mask, em, Wq, Wk, Wv, Wg0, Wg1,
            M, z, y, c2, segM, seg1, seg2, cnts, nbm, nb1, nb2,
            inv1, coefx, out, 1, 1);
        fused_all<<<NBUCK, 1024, 0, stream>>>(
            x, ei1, e1, ei2, e2, mask, em, Wq, Wk, Wv, Wg0, Wg1,
            M, z, y, c2, segM, seg1, seg2, cnts, nbm, nb1, nb2,
            inv1, coefx, out, 2, 2);
    }
}

// Round 7
// 62.164 us; speedup vs baseline: 5.5114x; 5.5114x over previous
//
#include <hip/hip_runtime.h>
#include <hip/hip_bf16.h>
#include <stdint.h>

#define NN 8192
#define DD 128

#define NBUCK 256          // bucket = d >> 5 (32 TARGET rows per bucket)
#define CHUNK 4096         // edges per partition chunk
#define SEGC 48            // per-(chunk,bucket) segment capacity (mean 16)
#define EPT 16             // CHUNK / 256
#define PCAP 128           // per-bucket passer capacity (mean ~8)

typedef __bf16 bf16x8 __attribute__((ext_vector_type(8)));
typedef float  f32x4  __attribute__((ext_vector_type(4)));

__device__ inline bf16x8 ld_bf16x8(const float* p) {
    float4 u0 = *(const float4*)p;
    float4 u1 = *(const float4*)(p + 4);
    bf16x8 r;
    r[0] = (__bf16)u0.x; r[1] = (__bf16)u0.y; r[2] = (__bf16)u0.z; r[3] = (__bf16)u0.w;
    r[4] = (__bf16)u1.x; r[5] = (__bf16)u1.y; r[6] = (__bf16)u1.z; r[7] = (__bf16)u1.w;
    return r;
}

// split fp32x8 into bf16 hi + lo residual (3-term MFMA ~ fp32 accuracy)
__device__ inline void ld_split(const float* p, bf16x8& h, bf16x8& l) {
    float4 u0 = *(const float4*)p;
    float4 u1 = *(const float4*)(p + 4);
    float v[8] = {u0.x, u0.y, u0.z, u0.w, u1.x, u1.y, u1.z, u1.w};
#pragma unroll
    for (int i = 0; i < 8; ++i) {
        __bf16 hh = (__bf16)v[i];
        h[i] = hh;
        l[i] = (__bf16)(v[i] - (float)hh);
    }
}

// ---- K1: M-gemm(fp32) + d-keyed packed radix partition ---------------------
// blocks: [0,64) M-gemm (+counter init) | [64, 64+npart) partition
__global__ __launch_bounds__(256) void k1_prep(
    const int* __restrict__ ei1, int e1,
    const int* __restrict__ ei2, int e2,
    const int* __restrict__ mask, int em,
    const float* __restrict__ Wq, const float* __restrict__ Wk,
    float* __restrict__ M, int* __restrict__ c2g, int* __restrict__ done,
    uint32_t* __restrict__ segM, uint32_t* __restrict__ seg1,
    uint32_t* __restrict__ seg2, int* __restrict__ counts,
    int nbm, int nb1, int nb2) {
    __shared__ int cnt[NBUCK];
    __shared__ int sc[2][NBUCK];
    __shared__ int startS[NBUCK];
    __shared__ int cur[NBUCK];
    __shared__ uint32_t stage[CHUNK];

    int bid = blockIdx.x;
    int t = threadIdx.x;

    if (bid < 64) {
        if (bid == 0 && t == 0) { *c2g = 0; *done = 0; }
        int c = bid * 2 + (t >> 7);
        int e = t & 127;
        float acc = 0.f;
#pragma unroll 8
        for (int a = 0; a < DD; ++a)
            acc += Wq[a * DD + c] * Wk[a * DD + e];
        M[c * DD + e] = acc;
        return;
    }
    int pb = bid - 64;
    const int* src; int ne, ch; uint32_t* seg; int* cnts;
    if (pb < nbm)            { src = mask; ne = em; ch = pb;             seg = segM; cnts = counts; }
    else if (pb < nbm + nb1) { src = ei1;  ne = e1; ch = pb - nbm;       seg = seg1; cnts = counts + nbm * NBUCK; }
    else                     { src = ei2;  ne = e2; ch = pb - nbm - nb1; seg = seg2; cnts = counts + (nbm + nb1) * NBUCK; }
    int base = ch * CHUNK;
    int n = ne - base;
    if (n > CHUNK) n = CHUNK;

    cnt[t] = 0;
    __syncthreads();

    // pack pk = (d << 13) | s  -> bucket = d>>5 = pk>>18; bit = pk & 0x3FFFF
    uint32_t pk[EPT];
#pragma unroll
    for (int k = 0; k < EPT; ++k) {
        int i = t + k * 256;
        if (i < n) {
            int s = src[base + i];
            int d = src[ne + base + i];
            pk[k] = ((uint32_t)d << 13) | (uint32_t)s;
            atomicAdd(&cnt[pk[k] >> 18], 1);
        } else pk[k] = 0xFFFFFFFFu;
    }
    __syncthreads();

    // inclusive scan of cnt
    sc[0][t] = cnt[t];
    __syncthreads();
    int sb = 0;
    for (int off = 1; off < NBUCK; off <<= 1) {
        int d2 = sb ^ 1;
        sc[d2][t] = (t >= off) ? sc[sb][t] + sc[sb][t - off] : sc[sb][t];
        sb = d2;
        __syncthreads();
    }
    int startv = (t == 0) ? 0 : sc[sb][t - 1];
    startS[t] = startv;
    cur[t] = startv;
    cnts[ch * NBUCK + t] = min(cnt[t], SEGC);
    __syncthreads();

    // bucket-sort into LDS
#pragma unroll
    for (int k = 0; k < EPT; ++k) {
        if (pk[k] != 0xFFFFFFFFu) {
            int b = pk[k] >> 18;
            int p = atomicAdd(&cur[b], 1);
            stage[p] = pk[k];
        }
    }
    __syncthreads();

    // coalesced flush to deterministic segments
    for (int i = t; i < n; i += 256) {
        uint32_t v = stage[i];
        int b = v >> 18;
        int off = i - startS[b];
        if (off < SEGC) seg[(ch * NBUCK + b) * SEGC + off] = v;
    }
}

// ---- K2: filter + slab-local A1/A2 + fused epilogue ------------------------
// bucket b exclusively owns target rows [32b, 32b+32): z/y accumulate in LDS,
// epilogue for those rows runs in the same block. Only global scalar: cnt2.
__global__ __launch_bounds__(1024) void k2_fused(
    const uint32_t* __restrict__ segM, const uint32_t* __restrict__ seg1,
    const uint32_t* __restrict__ seg2, const int* __restrict__ counts,
    const float* __restrict__ x, const float* __restrict__ Mg,
    const float* __restrict__ Wv, const float* __restrict__ Wg0,
    const float* __restrict__ Wg1,
    int* __restrict__ c2g, int* __restrict__ done,
    float inv_np1, float coef_x, float* __restrict__ out,
    int nbm, int nb1, int nb2) {
    __shared__ uint32_t bmap[8192];     // 32 KB: bit (d&31)*8192 + s
    __shared__ uint32_t seen[8192];     // 32 KB dedup
    __shared__ float zslab[32 * DD];    // 16 KB: A1 accumulator (own rows)
    __shared__ float yslab[32 * DD];    // 16 KB: A2 accumulator (own rows)
    __shared__ uint32_t pass[PCAP];
    __shared__ float xs[8][DD], xd[8][DD], red[8][2];
    __shared__ int pc;
    __shared__ float s2sh;

    int b = blockIdx.x;
    int t = threadIdx.x;
    const int* cntM  = counts;
    const int* cnt1c = counts + nbm * NBUCK;
    const int* cnt2c = counts + (nbm + nb1) * NBUCK;

    for (int i = t; i < 8192; i += 1024) { bmap[i] = 0; seen[i] = 0; }
    for (int i = t; i < 32 * DD; i += 1024) { zslab[i] = 0.f; yslab[i] = 0.f; }
    if (t == 0) pc = 0;
    __syncthreads();

    // build mask bitmap (duplicates harmless)
    int slotsM = nbm * SEGC;
    for (int i = t; i < slotsM; i += 1024) {
        int ch = i / SEGC, j = i - ch * SEGC;
        if (j < cntM[ch * NBUCK + b]) {
            uint32_t pk = segM[(ch * NBUCK + b) * SEGC + j];
            uint32_t bi = pk & 0x3FFFFu;
            atomicOr(&bmap[bi >> 5], 1u << (bi & 31));
        }
    }
    __syncthreads();

    // probe e1; dedup via seen
    int slots1 = nb1 * SEGC;
    for (int i = t; i < slots1; i += 1024) {
        int ch = i / SEGC, j = i - ch * SEGC;
        if (j < cnt1c[ch * NBUCK + b]) {
            uint32_t pk = seg1[(ch * NBUCK + b) * SEGC + j];
            uint32_t bi = pk & 0x3FFFFu;
            uint32_t m = 1u << (bi & 31);
            if (bmap[bi >> 5] & m) {
                uint32_t old = atomicOr(&seen[bi >> 5], m);
                if (!(old & m)) {
                    int pp = atomicAdd(&pc, 1);
                    if (pp < PCAP) pass[pp] = pk;
                }
            }
        }
    }
    __syncthreads();
    int np = min(pc, PCAP);
    int g = t >> 7, c = t & 127;

    // A1: zslab[d&31] += x[s]
    for (int p0 = 0; p0 < np; p0 += 8) {
        int e = p0 + g;
        if (e < np) {
            uint32_t pk = pass[e];
            int s = pk & 8191, d31 = (pk >> 13) & 31;
            atomicAdd(&zslab[d31 * DD + c], x[s * DD + c]);
        }
    }
    __syncthreads();
    if (t == 0) pc = 0;
    for (int i = t; i < 8192; i += 1024) seen[i] = 0;
    __syncthreads();

    // probe e2
    int slots2 = nb2 * SEGC;
    for (int i = t; i < slots2; i += 1024) {
        int ch = i / SEGC, j = i - ch * SEGC;
        if (j < cnt2c[ch * NBUCK + b]) {
            uint32_t pk = seg2[(ch * NBUCK + b) * SEGC + j];
            uint32_t bi = pk & 0x3FFFFu;
            uint32_t m = 1u << (bi & 31);
            if (bmap[bi >> 5] & m) {
                uint32_t old = atomicOr(&seen[bi >> 5], m);
                if (!(old & m)) {
                    int pp = atomicAdd(&pc, 1);
                    if (pp < PCAP) pass[pp] = pk;
                }
            }
        }
    }
    __syncthreads();
    np = min(pc, PCAP);
    // arrival: publish our count early; spin much later (slack = A2 + MFMA)
    if (t == 0) {
        __hip_atomic_fetch_add(c2g, np, __ATOMIC_RELAXED, __HIP_MEMORY_SCOPE_AGENT);
        __hip_atomic_fetch_add(done, 1, __ATOMIC_RELEASE, __HIP_MEMORY_SCOPE_AGENT);
    }

    // A2: yslab[d&31] += (x[d] @ M @ x[s]) * x[s]
    for (int p0 = 0; p0 < np; p0 += 8) {
        __syncthreads();
        int e = p0 + g;
        bool val = e < np;
        uint32_t pk = val ? pass[e] : 0;
        int s = pk & 8191;
        int d31 = (pk >> 13) & 31;
        if (val) {
            xs[g][c] = x[s * DD + c];
            xd[g][c] = x[((b << 5) + d31) * DD + c];
        }
        __syncthreads();
        if (val) {
            float acc = 0.f;
#pragma unroll 8
            for (int a = 0; a < DD; ++a)
                acc += xd[g][a] * Mg[a * DD + c];
            float part = acc * xs[g][c];
            for (int off2 = 32; off2; off2 >>= 1)
                part += __shfl_down(part, off2, 64);
            if ((c & 63) == 0) red[g][c >> 6] = part;
        }
        __syncthreads();
        if (val) {
            float se = red[g][0] + red[g][1];
            atomicAdd(&yslab[d31 * DD + c], se * xs[g][c]);
        }
    }
    __syncthreads();

    // epilogue for own 32 rows: 16 waves = 2 row-tiles x 8 col-strips
    int w = t >> 6, lane = t & 63;
    int tile = w >> 3, strip = w & 7;
    int i16 = lane & 15, kg = lane >> 4;
    int rowl = tile * 16;              // slab-local row base
    int rowg = (b << 5) + rowl;        // global row base
    int colbase = strip * 16;

    f32x4 acc = {}, acc2 = {};
#pragma unroll
    for (int kk = 0; kk < 8; ++kk) {
        int kofs = (kk & 3) * 32 + kg * 8;
        bf16x8 a = (kk < 4) ? ld_bf16x8(x + (rowg + i16) * DD + kofs)
                            : ld_bf16x8(&zslab[(rowl + i16) * DD + kofs]);
        const float* W = (kk < 4) ? Wg0 : Wg1;
        bf16x8 b0 = ld_bf16x8(W + (colbase + i16) * DD + kofs);
        acc = __builtin_amdgcn_mfma_f32_16x16x32_bf16(a, b0, acc, 0, 0, 0);
    }
#pragma unroll
    for (int kk = 0; kk < 4; ++kk) {
        int kofs = kk * 32 + kg * 8;
        bf16x8 yh, yl, wh, wl;
        ld_split(&yslab[(rowl + i16) * DD + kofs], yh, yl);
        ld_split(Wv + (colbase + i16) * DD + kofs, wh, wl);
        acc2 = __builtin_amdgcn_mfma_f32_16x16x32_bf16(yh, wh, acc2, 0, 0, 0);
        acc2 = __builtin_amdgcn_mfma_f32_16x16x32_bf16(yh, wl, acc2, 0, 0, 0);
        acc2 = __builtin_amdgcn_mfma_f32_16x16x32_bf16(yl, wh, acc2, 0, 0, 0);
    }

    // now wait for the global e2-count (all blocks long past arrival)
    if (t == 0) {
        while (__hip_atomic_load(done, __ATOMIC_ACQUIRE,
                                 __HIP_MEMORY_SCOPE_AGENT) < (int)gridDim.x)
            __builtin_amdgcn_s_sleep(8);
        int cv = __hip_atomic_load(c2g, __ATOMIC_RELAXED, __HIP_MEMORY_SCOPE_AGENT);
        s2sh = (float)NN / (float)cv;
    }
    __syncthreads();
    float scale2 = s2sh;

#pragma unroll
    for (int r = 0; r < 4; ++r) {
        int row = rowg + kg * 4 + r;
        int col = colbase + i16;
        float xv = x[row * DD + col];
        out[row * DD + col] = acc[r] * inv_np1 + coef_x * xv - acc2[r] * scale2;
    }
}

// ---- host ------------------------------------------------------------------

extern "C" void kernel_launch(void* const* d_in, const int* in_sizes, int n_in,
                              void* d_out, int out_size, void* d_ws, size_t ws_size,
                              hipStream_t stream) {
    const float* x   = (const float*)d_in[0];
    const int* ei1   = (const int*)d_in[1];
    const int* ei2   = (const int*)d_in[2];
    const int* mask  = (const int*)d_in[3];
    const float* Wg0 = (const float*)d_in[4];
    const float* Wg1 = (const float*)d_in[5];
    const float* Wq  = (const float*)d_in[6];
    const float* Wk  = (const float*)d_in[7];
    const float* Wv  = (const float*)d_in[8];
    float* out = (float*)d_out;

    int e1 = in_sizes[1] / 2;
    int e2 = in_sizes[2] / 2;
    int em = in_sizes[3] / 2;
    float np1 = (float)em / (float)NN;
    float inv1 = 1.0f / np1;
    float coefx = (np1 - 1.0f) * inv1;

    int nbm = (em + CHUNK - 1) / CHUNK;   // 128
    int nb1 = (e1 + CHUNK - 1) / CHUNK;   // 64
    int nb2 = (e2 + CHUNK - 1) / CHUNK;   // 64
    int npart = nbm + nb1 + nb2;          // 256

    char* ws = (char*)d_ws;
    const size_t O_M    = 0;                                   // 64 KB
    const size_t O_C2   = 65536;                               // c2, done
    const size_t O_CNTS = O_C2 + 64;                           // npart*256*4
    const size_t O_SEGM = O_CNTS + (size_t)npart * NBUCK * 4;
    const size_t O_SEG1 = O_SEGM + (size_t)nbm * NBUCK * SEGC * 4;
    const size_t O_SEG2 = O_SEG1 + (size_t)nb1 * NBUCK * SEGC * 4;
    // end ~ 13 MB

    float*    M     = (float*)(ws + O_M);
    int*      c2    = (int*)(ws + O_C2);
    int*      done  = (int*)(ws + O_C2 + 4);
    int*      cnts  = (int*)(ws + O_CNTS);
    uint32_t* segM  = (uint32_t*)(ws + O_SEGM);
    uint32_t* seg1  = (uint32_t*)(ws + O_SEG1);
    uint32_t* seg2  = (uint32_t*)(ws + O_SEG2);

    k1_prep<<<64 + npart, 256, 0, stream>>>(
        ei1, e1, ei2, e2, mask, em, Wq, Wk,
        M, c2, done, segM, seg1, seg2, cnts, nbm, nb1, nb2);
    k2_fused<<<NBUCK, 1024, 0, stream>>>(
        segM, seg1, seg2, cnts, x, M, Wv, Wg0, Wg1,
        c2, done, inv1, coefx, out, nbm, nb1, nb2);
}